// Round 7
// baseline (2555.359 us; speedup 1.0000x reference)
//
#include <hip/hip_runtime.h>

#define NN 1024
#define MM 1024
#define NB 16
#define BIGF 1.0e10f
#define NW 8                        // waves per workgroup
#define OFS 5                       // interval offset between adjacent waves
#define CW 16                       // steps (columns) per interval
#define NA 68                       // active intervals per wave (68*16 = 1088 steps)
#define NGI (OFS * (NW - 1) + NA)   // 103 global intervals

__device__ __forceinline__ float softmin3f(float a, float b, float c) {
  float mn = fminf(a, fminf(b, c));
  float s = __expf(mn - a) + __expf(mn - b) + __expf(mn - c);
  return mn - __logf(s);
}

// D[b,i,j] = (x[b,i] - y[j])^2 ; coalesced float4 writes
__global__ __launch_bounds__(256) void d_init_kernel(const float* __restrict__ x,
                                                     const float* __restrict__ y,
                                                     float* __restrict__ D) {
  size_t idx = ((size_t)blockIdx.x * blockDim.x + threadIdx.x) * 4;
  int j = (int)(idx & (MM - 1));
  size_t bi = idx >> 10;
  float xi = x[bi];
  const float4 yv = *reinterpret_cast<const float4*>(y + j);
  float t0 = xi - yv.x, t1 = xi - yv.y, t2 = xi - yv.z, t3 = xi - yv.w;
  float4 o;
  o.x = t0 * t0; o.y = t1 * t1; o.z = t2 * t2; o.w = t3 * t3;
  *reinterpret_cast<float4*>(D + idx) = o;
}

// R boundary: R[b,0,0]=0, R[b,0,j>=1]=BIG, R[b,i>=1,0]=BIG
__global__ __launch_bounds__(1024) void r_bound_kernel(float* __restrict__ R) {
  int b = blockIdx.x, t = threadIdx.x;
  float* Rb = R + (size_t)b * (NN + 1) * (MM + 1);
  Rb[t + 1] = BIGF;
  Rb[(size_t)(t + 1) * (MM + 1)] = BIGF;
  if (t == 0) Rb[0] = 0.0f;
}

// ---------------- forward ---------------------------------------------------
// Wave w owns rows 128w+1..128w+128; lane l owns i1=128w+2l+1, i2=i1+1.
// Lane l at step s computes col j = s - l. ONE shuffle per step (up); the
// diag value is the previous step's raw shuffle result (carry identity:
// dg(p+1) == raw_up(p), provable from the act-masked update rules).
__global__ __launch_bounds__(512) void sdtw_fwd(const float* __restrict__ x,
                                                const float* __restrict__ y,
                                                float* __restrict__ R,
                                                float* __restrict__ score) {
  __shared__ float tile[NW][2112];
  __shared__ float ringR[NW][128];
  const int b = blockIdx.x, t = threadIdx.x;
  const int w = t >> 6, l = t & 63;
  float* __restrict__ Rb = R + (size_t)b * (NN + 1) * (MM + 1);
  const int i1 = 128 * w + 2 * l + 1;
  const float x1 = x[b * NN + i1 - 1];
  const float x2 = x[b * NN + i1];
  float* tl = &tile[w][33 * l];
  const int wm1 = (w > 0) ? (w - 1) : 0;
  const bool L0 = (l == 0), W0 = (w == 0);
  const bool pub = (l == 63) && (w < NW - 1);
  float c1 = BIGF, c2 = BIGF, m1 = BIGF;
  float dgc = BIGF;  // carry: raw up-shuffle of previous step
  __syncthreads();
  for (int G = 0; G < NGI; ++G) {
    const int a = G - OFS * w;
    if (a >= 0 && a < NA) {
      const int s0 = a * CW;
      // hoisted inputs: y (global, L1-resident) + boundary ring (uniform LDS)
      float yw[16], rgm[17];
#pragma unroll
      for (int p = 0; p < 16; ++p) {
        const int jy = s0 + p - l - 1;
        yw[p] = y[(jy >= 0 && jy < MM) ? jy : 0];
      }
#pragma unroll
      for (int k = 0; k < 17; ++k) rgm[k] = ringR[wm1][(s0 + k - 1) & 127];
#pragma unroll
      for (int p = 0; p < CW; ++p) {
        const int j = s0 + p - l;
        const bool act = (j >= 1) && (j <= MM);
        const float up_raw = __shfl_up(m1, 1);  // R(i1-1, j)
        float up = up_raw;
        float dg = dgc;                          // R(i1-1, j-1) carry
        if (L0) {
          up = W0 ? BIGF : rgm[p + 1];
          dg = W0 ? ((j == 1) ? 0.0f : BIGF) : ((j == 1) ? BIGF : rgm[p]);
        }
        dgc = up_raw;
        const float yv = yw[p];
        float dv1 = x1 - yv; dv1 *= dv1;
        const float r1 = dv1 + softmin3f(dg, up, c1);
        float dv2 = x2 - yv; dv2 *= dv2;
        const float r2 = dv2 + softmin3f(c1, r1, c2);
        tl[p] = r1;
        tl[16 + p] = r2;
        if (pub && act) ringR[w][j & 127] = r2;
        m1 = act ? r2 : m1;
        c1 = act ? r1 : c1;
        c2 = act ? r2 : c2;
      }
      __builtin_amdgcn_wave_barrier();
      // cooperative coalesced store of window a (own wave's tile only)
#pragma unroll
      for (int g = 0; g < 32; ++g) {
        const int rr = 4 * g + (l >> 4);
        const int sl = l & 15;
        const int col = s0 + sl - (rr >> 1);
        const float v = tile[w][rr * 16 + (rr >> 1) + sl];
        if (col >= 1 && col <= MM)
          Rb[(size_t)(128 * w + 1 + rr) * (MM + 1) + col] = v;
      }
    }
    __syncthreads();
  }
  if (w == NW - 1 && l == 63) score[b] = m1;  // R[1024][1024]
}

// ---------------- backward --------------------------------------------------
// Wave w owns strip q=7-w; lane l owns i1=128q+2l+1, i2=i1+1; step s computes
// col j = 1087 - s - l (lane l+1 leads). TWO shuffles per step (dn E/R); the
// diag values are the previous step's raw shuffle results (carry identity).
// R of the current window is hoisted from the tile into registers upfront
// (batched ds_reads, off the chain); E overwrites the tile in place; coop
// phase stores E coalesced and reloads next window's R branch-free.
__global__ __launch_bounds__(512) void sdtw_bwd(const float* __restrict__ x,
                                                const float* __restrict__ y,
                                                const float* __restrict__ R,
                                                float* __restrict__ E) {
  __shared__ float tile[NW][2112];
  __shared__ float ringEl[NW][128];
  __shared__ float ringRl[NW][128];
  const int b = blockIdx.x, t = threadIdx.x;
  const int w = t >> 6, l = t & 63;
  const int q = NW - 1 - w;  // strip (rows 128q+1 .. 128q+128)
  const float* __restrict__ Rb = R + (size_t)b * (NN + 1) * (MM + 1);
  float* __restrict__ Eb = E + (size_t)b * (size_t)NN * MM;
  const int i1 = 128 * q + 2 * l + 1, i2 = i1 + 1;
  const float xa = x[b * NN + i1 - 1];                       // x(i1)
  const float xb = x[b * NN + i1];                           // x(i2)
  const float xc = x[b * NN + ((i2 < NN) ? i2 : (NN - 1))];  // x(i2+1), clamped
  const bool vdn2 = (i2 < NN);
  const bool seedL = (i2 == NN);  // only wave 0 lane 63
  float* tl = &tile[w][33 * l];
  const int wm1 = (w > 0) ? (w - 1) : 0;
  const bool L63 = (l == 63);
  const bool pub = (l == 0) && (w < NW - 1);
  float a1e = 0.f, a1r = -BIGF;   // own i1 history (E, R)
  float b1e = 0.f, b1r = -BIGF;   // own i2 history
  float dgEc = 0.f, dgRc = -BIGF; // carries: raw dn-shuffles of previous step
  // prologue: coop-load R window a=0 into tile (branch-free masked loads)
#pragma unroll
  for (int g = 0; g < 32; ++g) {
    const int rr = 4 * g + (l >> 4);
    const int sl = l & 15;
    const int col = 1087 - sl - (rr >> 1);
    const float v = (col >= 1 && col <= MM)
                        ? Rb[(size_t)(128 * q + 1 + rr) * (MM + 1) + col]
                        : -BIGF;
    tile[w][rr * 16 + (rr >> 1) + sl] = v;
  }
  __syncthreads();
  for (int G = 0; G < NGI; ++G) {
    const int a = G - OFS * w;
    if (a >= 0 && a < NA) {
      const int s0 = a * CW;
      // hoisted: own-window R from tile (batched, off-chain)
      float rr1[16], rr2[16];
#pragma unroll
      for (int p = 0; p < 16; ++p) { rr1[p] = tl[p]; rr2[p] = tl[16 + p]; }
      // hoisted: y (global) + boundary rings (uniform LDS reads)
      float yw[16], rgE[17], rgR[17];
#pragma unroll
      for (int p = 0; p < 16; ++p) {
        const int jy = 1086 - s0 - p - l;  // j-1 at step p
        yw[p] = y[(jy >= 0 && jy < MM) ? jy : 0];
      }
#pragma unroll
      for (int k = 0; k < 17; ++k) {
        const int idx = (1025 - s0 - k) & 127;
        rgE[k] = ringEl[wm1][idx];
        rgR[k] = ringRl[wm1][idx];
      }
      float yjc;
      {
        const int jy0 = 1087 - s0 - l;  // y[j] at step p=0
        yjc = (jy0 >= 0 && jy0 < MM) ? y[jy0] : 0.0f;
      }
      // 16-step compute: chain = 2 shuffles + exp VALU only
#pragma unroll
      for (int p = 0; p < CW; ++p) {
        const int j = 1087 - (s0 + p) - l;
        const bool act = (j >= 1) && (j <= MM);
        const bool vrt = (j < MM);
        const float dnE_raw = __shfl_down(a1e, 1);  // E(i2+1, j)
        const float dnR_raw = __shfl_down(a1r, 1);
        float dnE = dnE_raw, dnR = dnR_raw;
        float dgE = dgEc, dgR = dgRc;               // E/R(i2+1, j+1) carries
        if (L63) { dnE = rgE[p + 1]; dnR = rgR[p + 1]; dgE = rgE[p]; dgR = rgR[p]; }
        dgEc = dnE_raw; dgRc = dnR_raw;
        const float yjm = yw[p];
        const float rij2 = rr2[p];
        const float rij1 = rr1[p];
        // i2 cell
        float d1 = xc - yjm; d1 *= d1;  // D(i2+1, j)
        float d2 = xb - yjc; d2 *= d2;  // D(i2, j+1) == D(i1+1, j+1)
        float d3 = xc - yjc; d3 *= d3;  // D(i2+1, j+1)
        const float t1 = vdn2 ? (dnR - rij2 - d1) : -BIGF;
        const float t2 = vrt ? (b1r - rij2 - d2) : -BIGF;
        const float t3 = (vdn2 && vrt) ? (dgR - rij2 - d3) : -BIGF;
        float e2 = dnE * __expf(t1) + b1e * __expf(t2) + dgE * __expf(t3);
        if (seedL && j == MM) e2 += 1.0f;
        // i1 cell (dn = fresh i2 values)
        float d4 = xb - yjm; d4 *= d4;  // D(i1+1, j)
        float d5 = xa - yjc; d5 *= d5;  // D(i1, j+1)
        const float u1 = rij2 - rij1 - d4;
        const float u2 = vrt ? (a1r - rij1 - d5) : -BIGF;
        const float u3 = vrt ? (b1r - rij1 - d2) : -BIGF;  // D(i1+1,j+1)==d2
        const float e1 = e2 * __expf(u1) + a1e * __expf(u2) + b1e * __expf(u3);
        tl[p] = e1;       // in-place E over R (consumed by coop phase)
        tl[16 + p] = e2;
        if (pub && act) { ringEl[w][j & 127] = e1; ringRl[w][j & 127] = rij1; }
        a1e = act ? e1 : a1e;  a1r = act ? rij1 : a1r;
        b1e = act ? e2 : b1e;  b1r = act ? rij2 : b1r;
        yjc = yjm;
      }
      __builtin_amdgcn_wave_barrier();
      // coop: store E window a, then reload R window a+1 (branch-free masked)
#pragma unroll
      for (int g = 0; g < 32; ++g) {
        const int rr = 4 * g + (l >> 4);
        const int sl = l & 15;
        const int col = 1087 - s0 - sl - (rr >> 1);
        const int ad = rr * 16 + (rr >> 1) + sl;
        const float v = tile[w][ad];
        if (col >= 1 && col <= MM)
          Eb[(size_t)(128 * q + rr) * MM + (col - 1)] = v;
        const int colN = col - CW;
        const float rv = (colN >= 1 && colN <= MM)
                             ? Rb[(size_t)(128 * q + 1 + rr) * (MM + 1) + colN]
                             : -BIGF;
        tile[w][ad] = rv;
      }
    }
    __syncthreads();
  }
}

extern "C" void kernel_launch(void* const* d_in, const int* in_sizes, int n_in,
                              void* d_out, int out_size, void* d_ws, size_t ws_size,
                              hipStream_t stream) {
  const float* x = (const float*)d_in[0];  // [16, 1024]
  const float* y = (const float*)d_in[1];  // [1024]
  float* out = (float*)d_out;
  float* score = out;                               // [16]
  float* D = out + NB;                              // [16,1024,1024]
  float* R = D + (size_t)NB * NN * MM;              // [16,1025,1025]
  float* E = R + (size_t)NB * (NN + 1) * (MM + 1);  // [16,1024,1024]

  hipLaunchKernelGGL(d_init_kernel, dim3((NB * NN * MM) / (256 * 4)), dim3(256), 0, stream,
                     x, y, D);
  hipLaunchKernelGGL(r_bound_kernel, dim3(NB), dim3(1024), 0, stream, R);
  hipLaunchKernelGGL(sdtw_fwd, dim3(NB), dim3(512), 0, stream, x, y, R, score);
  hipLaunchKernelGGL(sdtw_bwd, dim3(NB), dim3(512), 0, stream, x, y, R, E);
}

// Round 8
// 1653.876 us; speedup vs baseline: 1.5451x; 1.5451x over previous
//
#include <hip/hip_runtime.h>

#define NN 1024
#define MM 1024
#define NB 16
#define BIGF 1.0e10f
#define TP 17  // padded tile row stride (bank-conflict-free)

typedef float f32x4 __attribute__((ext_vector_type(4)));

__device__ __forceinline__ float softmin3f(float a, float b, float c) {
  float mn = fminf(a, fminf(b, c));
  float s = __expf(mn - a) + __expf(mn - b) + __expf(mn - c);
  return mn - __logf(s);
}

// D[b,i,j] = (x[b,i] - y[j])^2 ; coalesced float4 writes
__global__ __launch_bounds__(256) void d_init_kernel(const float* __restrict__ x,
                                                     const float* __restrict__ y,
                                                     float* __restrict__ D) {
  size_t idx = ((size_t)blockIdx.x * blockDim.x + threadIdx.x) * 4;
  int j = (int)(idx & (MM - 1));
  size_t bi = idx >> 10;
  float xi = x[bi];
  const float4 yv = *reinterpret_cast<const float4*>(y + j);
  float t0 = xi - yv.x, t1 = xi - yv.y, t2 = xi - yv.z, t3 = xi - yv.w;
  float4 o;
  o.x = t0 * t0; o.y = t1 * t1; o.z = t2 * t2; o.w = t3 * t3;
  *reinterpret_cast<float4*>(D + idx) = o;
}

// R boundary: R[b,0,0]=0, R[b,0,j>=1]=BIG, R[b,i>=1,0]=BIG
__global__ __launch_bounds__(1024) void r_bound_kernel(float* __restrict__ R) {
  int b = blockIdx.x, t = threadIdx.x;
  float* Rb = R + (size_t)b * (NN + 1) * (MM + 1);
  Rb[t + 1] = BIGF;
  Rb[(size_t)(t + 1) * (MM + 1)] = BIGF;
  if (t == 0) Rb[0] = 0.0f;
}

// Forward DP: thread t owns row i=t+1. Single diag-indexed LDS tile
// tile[row i][slot p] (row 0 = static boundary). Per-step chain: write
// tile[i][p] -> barrier -> neighbor reads tile[i-1][p-1]. dg is the carry of
// the previous step's up. y hoisted to registers per 16-diag block. Tile is
// coop-stored coalesced per block (4 lanes x float4 per row).
__global__ __launch_bounds__(1024) void sdtw_fwd(const float* __restrict__ x,
                                                 const float* __restrict__ y,
                                                 float* __restrict__ R,
                                                 float* __restrict__ score) {
  __shared__ float tile[NN + 1][TP];  // tile[r][p] = R(r, d0+p-r), BIG if invalid
  const int b = blockIdx.x, t = threadIdx.x;
  const int i = t + 1;
  float* __restrict__ Rb = R + (size_t)b * (NN + 1) * (MM + 1);
  if (t < TP) tile[0][t] = (t == 0) ? 0.0f : BIGF;  // boundary row R(0, *)
  const float xi = x[b * NN + t];
  float dgc = BIGF;  // carry: previous step's up (= R(i-1, j-1) now)
  float cc = BIGF;   // own R(i, j-1)
  __syncthreads();
  for (int blk = 0; blk <= 128; ++blk) {
    const int d0 = blk << 4;
    float yw[16];
#pragma unroll
    for (int p = 0; p < 16; ++p) {
      const int idx = d0 + p - i - 1;  // j-1 at step p
      yw[p] = y[min(MM - 1, max(0, idx))];
    }
#pragma unroll
    for (int p = 0; p < 16; ++p) {
      const int j = d0 + p - i;
      const bool act = (j >= 1) && (j <= MM);
      // up = R(i-1, j): neighbor's slot p-1 (slot 15 = previous block's tail)
      const float up = (p == 0) ? tile[t][15] : tile[t][p - 1];
      const float dg = dgc;  // R(i-1, j-1)
      dgc = up;
      float dv = xi - yw[p]; dv *= dv;
      const float r = dv + softmin3f(dg, up, cc);
      tile[i][p] = act ? r : BIGF;
      if (act) cc = r;
      if (blk == 128 && p == 0 && t == NN - 1) score[b] = r;  // R[N][M]
      __syncthreads();
    }
    // cooperative coalesced store: 4 lanes/row, float4 each
#pragma unroll
    for (int pass = 0; pass < 4; ++pass) {
      const int row = (pass << 8) + (t >> 2);  // 0..1023
      const int ir = row + 1;
      const int c4 = (t & 3) << 2;
      const int jb2 = d0 - ir + c4;
      float fv[4];
#pragma unroll
      for (int c = 0; c < 4; ++c) fv[c] = tile[ir][c4 + c];
      if (jb2 >= 1 && jb2 + 3 <= MM) {
        *reinterpret_cast<float4*>(Rb + (size_t)ir * (MM + 1) + jb2) =
            make_float4(fv[0], fv[1], fv[2], fv[3]);
      } else if (jb2 + 3 >= 1 && jb2 <= MM) {
#pragma unroll
        for (int c = 0; c < 4; ++c) {
          const int jc = jb2 + c;
          if (jc >= 1 && jc <= MM) Rb[(size_t)ir * (MM + 1) + jc] = fv[c];
        }
      }
    }
    if (blk == 0 && t == 0) tile[0][0] = BIGF;  // R(0, d>=16) boundary is BIG
    __syncthreads();  // protect tile before next block overwrites
  }
}

// Backward: Rbar(i,j) = seed + E_dn*exp(R_dn-rij-D_dn) + E_rt*exp(R_rt-rij-D_rt)
//                      + E_dg*exp(R_dg-rij-D_dg); E[i-1][j-1] = Rbar(i,j).
// Split tiles: rtile holds the R window (stable all block -> neighbor R reads
// are off-chain), etile holds computed E (per-step chain = 1 write + 1 read).
// Seam: etile slot 0 retains the previous block's E until step s=0; the R seam
// value is carried in a register (rnb0) across blocks. Coop phase: store E,
// reload next R window. y hoisted per block.
__global__ __launch_bounds__(1024) void sdtw_bwd(const float* __restrict__ x,
                                                 const float* __restrict__ y,
                                                 const float* __restrict__ R,
                                                 float* __restrict__ E) {
  __shared__ float rtile[NN + 1][TP];  // row r = R-row r+1; row NN = -BIG pad
  __shared__ float etile[NN + 1][TP];  // row r = E-row r+1; row NN = 0 pad
  const int b = blockIdx.x, t = threadIdx.x;
  const int i = t + 1;
  const float* __restrict__ Rb = R + (size_t)b * (NN + 1) * (MM + 1);
  float* __restrict__ Eb = E + (size_t)b * (size_t)NN * MM;
  const float xi = x[b * NN + t];                              // X(i)
  const float xi1 = x[b * NN + ((t + 1 < NN) ? (t + 1) : t)];  // X(i+1)
  const bool idn = (i + 1 <= NN);
  const bool seedrow = (i == NN);
  float rt_e = 0.0f, rt_r = -BIGF;    // (i, j+1) carries
  float dgn_e = 0.0f, dgn_r = -BIGF;  // (i+1, j+1) carries
  float rnb0 = -BIGF;                 // R(i+1) @ diag d0+16 (seam, reg carry)
  if (t < TP) { rtile[NN][t] = -BIGF; etile[NN][t] = 0.0f; }  // pads (row 1025)
  // prologue: coop-load R window for K=128
#pragma unroll
  for (int pass = 0; pass < 4; ++pass) {
    const int row = (pass << 8) + (t >> 2);
    const int ir = row + 1;
    const int c4 = (t & 3) << 2;
    const int jb2 = (128 << 4) - ir + c4;
    if (jb2 >= 1 && jb2 + 3 <= MM) {
      const float4 v = *reinterpret_cast<const float4*>(Rb + (size_t)ir * (MM + 1) + jb2);
      rtile[row][c4] = v.x; rtile[row][c4 + 1] = v.y;
      rtile[row][c4 + 2] = v.z; rtile[row][c4 + 3] = v.w;
    } else {
#pragma unroll
      for (int c = 0; c < 4; ++c) {
        const int jc = jb2 + c;
        rtile[row][c4 + c] =
            (jc >= 1 && jc <= MM) ? Rb[(size_t)ir * (MM + 1) + jc] : -BIGF;
      }
    }
  }
  __syncthreads();

  for (int K = 128; K >= 0; --K) {
    const int d0 = K << 4;
    float yw[17];
#pragma unroll
    for (int s = 0; s < 17; ++s) {
      const int idx = d0 + s - i - 1;  // y[j-1] at step s; yw[16] = y[j] at s=15
      yw[s] = y[min(MM - 1, max(0, idx))];
    }
    float yjc = yw[16];
    const float rnb0_next = rtile[t + 1][0];  // R(i+1) @ diag d0 (for block K-1)
#pragma unroll
    for (int p = 0; p < 16; ++p) {
      const int s = 15 - p;  // descending diag within block
      const int j = d0 + s - i;
      const bool act = (j >= 1) && (j <= MM);
      const bool vrt = (j < MM);
      // E(i+1, j) @ diag d+1: slot (s+1)&15 (slot 0 = stale prev-block value)
      const float dn_e = etile[t + 1][(s + 1) & 15];
      const float dn_r = (s == 15) ? rnb0 : rtile[t + 1][s + 1];
      const float rij = rtile[t][s];
      const float yjm = yw[s];
      float d1 = xi1 - yjm; d1 *= d1;  // D(i+1, j)
      float d2 = xi - yjc;  d2 *= d2;  // D(i,   j+1)
      float d3 = xi1 - yjc; d3 *= d3;  // D(i+1, j+1)
      const float a1 = idn ? (dn_r - rij - d1) : -BIGF;
      const float a2 = vrt ? (rt_r - rij - d2) : -BIGF;
      const float a3 = (idn && vrt) ? (dgn_r - rij - d3) : -BIGF;
      float acc = dn_e * __expf(a1) + rt_e * __expf(a2) + dgn_e * __expf(a3);
      if (seedrow && j == MM) acc += 1.0f;
      etile[t][s] = act ? acc : 0.0f;
      rt_e = act ? acc : 0.0f;
      rt_r = act ? rij : -BIGF;
      dgn_e = dn_e; dgn_r = dn_r;
      yjc = yjm;
      __syncthreads();
    }
    rnb0 = rnb0_next;
    // coop: store E window, then reload R window for block K-1
#pragma unroll
    for (int pass = 0; pass < 4; ++pass) {
      const int row = (pass << 8) + (t >> 2);
      const int ir = row + 1;
      const int c4 = (t & 3) << 2;
      const int jb2 = d0 - ir + c4;
      float fv[4];
#pragma unroll
      for (int c = 0; c < 4; ++c) fv[c] = etile[row][c4 + c];
      if (jb2 >= 1 && jb2 + 3 <= MM) {
        f32x4 v;
        v[0] = fv[0]; v[1] = fv[1]; v[2] = fv[2]; v[3] = fv[3];
        const float* pp = Eb + (size_t)row * MM + (jb2 - 1);
        asm volatile("global_store_dwordx4 %0, %1, off" ::"v"(pp), "v"(v) : "memory");
      } else if (jb2 + 3 >= 1 && jb2 <= MM) {
#pragma unroll
        for (int c = 0; c < 4; ++c) {
          const int jc = jb2 + c;
          if (jc >= 1 && jc <= MM) Eb[(size_t)row * MM + (jc - 1)] = fv[c];
        }
      }
      const int jn = jb2 - 16;  // next block window
      if (jn >= 1 && jn + 3 <= MM) {
        const float4 v = *reinterpret_cast<const float4*>(Rb + (size_t)ir * (MM + 1) + jn);
        rtile[row][c4] = v.x; rtile[row][c4 + 1] = v.y;
        rtile[row][c4 + 2] = v.z; rtile[row][c4 + 3] = v.w;
      } else {
#pragma unroll
        for (int c = 0; c < 4; ++c) {
          const int jc = jn + c;
          rtile[row][c4 + c] =
              (jc >= 1 && jc <= MM) ? Rb[(size_t)ir * (MM + 1) + jc] : -BIGF;
        }
      }
    }
    __syncthreads();
  }
}

extern "C" void kernel_launch(void* const* d_in, const int* in_sizes, int n_in,
                              void* d_out, int out_size, void* d_ws, size_t ws_size,
                              hipStream_t stream) {
  const float* x = (const float*)d_in[0];  // [16, 1024]
  const float* y = (const float*)d_in[1];  // [1024]
  float* out = (float*)d_out;
  float* score = out;                               // [16]
  float* D = out + NB;                              // [16,1024,1024]
  float* R = D + (size_t)NB * NN * MM;              // [16,1025,1025]
  float* E = R + (size_t)NB * (NN + 1) * (MM + 1);  // [16,1024,1024]

  hipLaunchKernelGGL(d_init_kernel, dim3((NB * NN * MM) / (256 * 4)), dim3(256), 0, stream,
                     x, y, D);
  hipLaunchKernelGGL(r_bound_kernel, dim3(NB), dim3(1024), 0, stream, R);
  hipLaunchKernelGGL(sdtw_fwd, dim3(NB), dim3(1024), 0, stream, x, y, R, score);
  hipLaunchKernelGGL(sdtw_bwd, dim3(NB), dim3(1024), 0, stream, x, y, R, E);
}